// Round 12
// baseline (100.427 us; speedup 1.0000x reference)
//
#include <hip/hip_runtime.h>
#include <math.h>

#define EPS 1e-8f
#define MARGIN 0.5f
#define NEG_PER_WAVE 32
#define FIXSCALE 1048576.0f            // 2^20 fixed-point for t
#define MASK40 ((1ULL << 40) - 1)

typedef float    f4 __attribute__((ext_vector_type(4)));
typedef _Float16 h4 __attribute__((ext_vector_type(4)));

__device__ __forceinline__ float dot4(const f4 a, const f4 b) {
    return a.x * b.x + a.y * b.y + a.z * b.z + a.w * b.w;
}
__device__ __forceinline__ float dot4h(const h4 a, const f4 b) {
    return (float)a.x * b.x + (float)a.y * b.y + (float)a.z * b.z + (float)a.w * b.w;
}

// ==================== Sorted fp16-anchor path (tier 1) ======================

// Kernel 1s: pos cosine + normalized fp16 anchor table + zero u64 accums
// + histogram of idx into cnt (cnt pre-zeroed by memset).
__global__ void pos_hist_kernel(const float* __restrict__ anchor,
                                const float* __restrict__ pos,
                                const int*  __restrict__ idx,
                                _Float16* __restrict__ a_h,
                                float* __restrict__ ps,
                                unsigned long long* __restrict__ acc,
                                unsigned* __restrict__ cnt,
                                int B, int N) {
    const int tid  = blockIdx.x * blockDim.x + threadIdx.x;
    const int row  = tid >> 6;
    const int lane = threadIdx.x & 63;
    const int tot  = gridDim.x * blockDim.x;

    // zero packed accumulators (2*B u32 words; total threads = 64*B >= 2*B)
    if (tid < 2 * B) ((unsigned int*)acc)[tid] = 0u;

    // histogram (grid-stride; tot = 64*B >= N here, so usually 1 iter)
    for (long long i = tid; i < N; i += tot)
        atomicAdd(&cnt[idx[i]], 1u);

    if (row >= B) return;

    const f4 a = *(reinterpret_cast<const f4*>(anchor + (size_t)row * 256) + lane);
    const f4 p = *(reinterpret_cast<const f4*>(pos    + (size_t)row * 256) + lane);

    float dot = dot4(a, p);
    float na  = dot4(a, a);
    float nb  = dot4(p, p);

    #pragma unroll
    for (int off = 32; off > 0; off >>= 1) {
        dot += __shfl_xor(dot, off);
        na  += __shfl_xor(na,  off);
        nb  += __shfl_xor(nb,  off);
    }
    const float sna   = sqrtf(na);
    const float scale = 1.0f / fmaxf(sna, 1e-20f);

    h4 ah;
    ah.x = (_Float16)(a.x * scale);
    ah.y = (_Float16)(a.y * scale);
    ah.z = (_Float16)(a.z * scale);
    ah.w = (_Float16)(a.w * scale);
    *(reinterpret_cast<h4*>(a_h + (size_t)row * 256) + lane) = ah;

    if (lane == 0)
        ps[row] = dot / fmaxf(sna * sqrtf(nb), EPS);
}

// Kernel 1b: exclusive prefix sum cnt -> off (B <= 4096, one block).
__global__ void __launch_bounds__(1024) scan_kernel(
        const unsigned* __restrict__ cnt,
        unsigned* __restrict__ off, int B) {
    __shared__ unsigned tsum[1024];
    const int t = threadIdx.x;
    unsigned c[4];
    unsigned s = 0;
    #pragma unroll
    for (int j = 0; j < 4; ++j) {
        const int i = t * 4 + j;
        c[j] = (i < B) ? cnt[i] : 0u;
        s += c[j];
    }
    tsum[t] = s;
    __syncthreads();
    for (int o = 1; o < 1024; o <<= 1) {
        const unsigned v = (t >= o) ? tsum[t - o] : 0u;
        __syncthreads();
        tsum[t] += v;
        __syncthreads();
    }
    unsigned pre = (t > 0) ? tsum[t - 1] : 0u;
    #pragma unroll
    for (int j = 0; j < 4; ++j) {
        const int i = t * 4 + j;
        if (i < B) off[i] = pre;
        pre += c[j];
    }
}

// Kernel 1c: scatter negatives into bucket order. sorted[p] = (b<<32)|n.
// (Order within a bucket is nondeterministic, but the final integer sums
// are order-independent -> deterministic output.)
__global__ void scatter_kernel(const int* __restrict__ idx,
                               unsigned* __restrict__ off,
                               unsigned long long* __restrict__ sorted,
                               int N) {
    const int i = blockIdx.x * blockDim.x + threadIdx.x;
    if (i < N) {
        const int b = idx[i];
        const unsigned p = atomicAdd(&off[b], 1u);
        sorted[p] = ((unsigned long long)(unsigned)b << 32) | (unsigned)i;
    }
}

// Kernel 2s: negatives in bucket order. a_h row is shared across a run ->
// L1 hits (gather traffic ~2 MB instead of 128 MB). Flush does a wave-level
// segmented reduction (exact integer pk sums) -> ~1 atomic per run per wave.
__global__ void __launch_bounds__(256) neg_h_sorted(
        const _Float16* __restrict__ a_h,
        const float* __restrict__ neg,
        const unsigned long long* __restrict__ sorted,
        const float* __restrict__ ps,
        unsigned long long* __restrict__ acc,
        int N) {
    __shared__ float ssim[4][NEG_PER_WAVE];

    const int lane  = threadIdx.x & 63;
    const int wid   = threadIdx.x >> 6;
    const int group = lane >> 4;
    const int glane = lane & 15;
    const long long base =
        ((long long)blockIdx.x * (blockDim.x >> 6) + wid) * NEG_PER_WAVE;

    // lanes 0..31 hold this wave's 32 sorted entries
    int b_all = -1, n_all = 0;
    if (lane < NEG_PER_WAVE) {
        const long long ii = base + lane;
        if (ii < N) {
            const unsigned long long e = sorted[ii];
            b_all = (int)(e >> 32);
            n_all = (int)(e & 0xffffffffu);
        }
    }

    if (base < N) {
        #pragma unroll 2
        for (int it = 0; it < NEG_PER_WAVE; it += 4) {
            const bool valid = (base + it + group) < N;
            const int b = __shfl(b_all, it + group);
            const int n = __shfl(n_all, it + group);
            const int nn = valid ? n : 0;
            const int bb = valid ? b : 0;

            const f4* nr = reinterpret_cast<const f4*>(neg + (size_t)nn * 256);
            const h4* ar = reinterpret_cast<const h4*>(a_h + (size_t)bb * 256);

            const f4 v0 = nr[ 0 + glane];
            const f4 v1 = nr[16 + glane];
            const f4 v2 = nr[32 + glane];
            const f4 v3 = nr[48 + glane];
            const h4 a0 = ar[ 0 + glane], a1 = ar[16 + glane],
                     a2 = ar[32 + glane], a3 = ar[48 + glane];

            float d = dot4h(a0, v0) + dot4h(a1, v1) + dot4h(a2, v2) + dot4h(a3, v3);
            float q = dot4(v0, v0) + dot4(v1, v1) + dot4(v2, v2) + dot4(v3, v3);

            #pragma unroll
            for (int off = 8; off > 0; off >>= 1) {
                d += __shfl_xor(d, off);
                q += __shfl_xor(q, off);
            }
            if (glane == 0 && valid)
                ssim[wid][it + group] = d * rsqrtf(fmaxf(q, 1e-30f));
        }
    }

    // ---- flush: wave-level segmented reduction over sorted runs ----
    unsigned long long pk = 0;
    int bseg = -1;
    if (lane < NEG_PER_WAVE && base + lane < N) {
        bseg = b_all;
        const float t = fmaxf(MARGIN + ssim[wid][lane] - ps[bseg], 0.0f);
        pk = (unsigned long long)(t * FIXSCALE + 0.5f) + (1ULL << 40);
    }
    #pragma unroll
    for (int o = 1; o < NEG_PER_WAVE; o <<= 1) {
        const int nb = __shfl_down(bseg, o);
        const unsigned long long nv = __shfl_down(pk, o);
        if (lane + o < 64 && nb == bseg) pk += nv;
    }
    if (bseg >= 0) {
        const int pb = __shfl_up(bseg, 1);
        if (lane == 0 || pb != bseg)
            atomicAdd(&acc[bseg], pk);
    }
}

// Kernel 3: unpack u64 accums -> segment means -> scalar (one block).
__global__ void __launch_bounds__(1024) finalize_packed_kernel(
        const unsigned long long* __restrict__ acc,
        float* __restrict__ out, int B) {
    float local = 0.0f;
    for (int i = threadIdx.x; i < B; i += blockDim.x) {
        const unsigned long long v = acc[i];
        const float c = (float)(v >> 40);
        const float s = (float)(v & MASK40) * (1.0f / FIXSCALE);
        local += (c > 0.0f) ? (s / c) : 0.0f;
    }
    #pragma unroll
    for (int off = 32; off > 0; off >>= 1)
        local += __shfl_xor(local, off);

    __shared__ float ws[16];
    const int wid = threadIdx.x >> 6;
    if ((threadIdx.x & 63) == 0) ws[wid] = local;
    __syncthreads();
    if (threadIdx.x == 0) {
        float tot = 0.0f;
        const int nw = blockDim.x >> 6;
        for (int w = 0; w < nw; ++w) tot += ws[w];
        out[0] = tot / (float)B;
    }
}

// ============ Tier 2: unsorted fp16 path (R10, proven 61.8 µs) ==============

__global__ void pos_h_kernel(const float* __restrict__ anchor,
                             const float* __restrict__ pos,
                             _Float16* __restrict__ a_h,
                             float* __restrict__ ps,
                             unsigned long long* __restrict__ acc,
                             int B) {
    const int tid  = blockIdx.x * blockDim.x + threadIdx.x;
    const int row  = tid >> 6;
    const int lane = threadIdx.x & 63;

    if (tid < 2 * B) ((unsigned int*)acc)[tid] = 0u;
    if (row >= B) return;

    const f4 a = *(reinterpret_cast<const f4*>(anchor + (size_t)row * 256) + lane);
    const f4 p = *(reinterpret_cast<const f4*>(pos    + (size_t)row * 256) + lane);

    float dot = dot4(a, p), na = dot4(a, a), nb = dot4(p, p);
    #pragma unroll
    for (int off = 32; off > 0; off >>= 1) {
        dot += __shfl_xor(dot, off);
        na  += __shfl_xor(na,  off);
        nb  += __shfl_xor(nb,  off);
    }
    const float sna   = sqrtf(na);
    const float scale = 1.0f / fmaxf(sna, 1e-20f);
    h4 ah;
    ah.x = (_Float16)(a.x * scale); ah.y = (_Float16)(a.y * scale);
    ah.z = (_Float16)(a.z * scale); ah.w = (_Float16)(a.w * scale);
    *(reinterpret_cast<h4*>(a_h + (size_t)row * 256) + lane) = ah;
    if (lane == 0) ps[row] = dot / fmaxf(sna * sqrtf(nb), EPS);
}

__global__ void __launch_bounds__(256) neg_h_kernel(
        const _Float16* __restrict__ a_h,
        const float* __restrict__ neg,
        const int*  __restrict__ idx,
        const float* __restrict__ ps,
        unsigned long long* __restrict__ acc,
        int N) {
    __shared__ float ssim[4][NEG_PER_WAVE];
    const int lane  = threadIdx.x & 63;
    const int wid   = threadIdx.x >> 6;
    const int group = lane >> 4;
    const int glane = lane & 15;
    const long long base =
        ((long long)blockIdx.x * (blockDim.x >> 6) + wid) * NEG_PER_WAVE;

    int b_all = 0;
    {
        const long long in = base + lane;
        if (lane < NEG_PER_WAVE && in < N) b_all = idx[in];
    }
    if (base < N) {
        #pragma unroll 2
        for (int it = 0; it < NEG_PER_WAVE; it += 4) {
            const long long n = base + it + group;
            const bool valid = (n < N);
            const long long ns = valid ? n : (long long)0;
            const int b = __shfl(b_all, it + group);

            const f4* nr = reinterpret_cast<const f4*>(neg + (size_t)ns * 256);
            const h4* ar = reinterpret_cast<const h4*>(a_h + (size_t)b * 256);
            const f4 v0 = nr[ 0 + glane], v1 = nr[16 + glane],
                     v2 = nr[32 + glane], v3 = nr[48 + glane];
            const h4 a0 = ar[ 0 + glane], a1 = ar[16 + glane],
                     a2 = ar[32 + glane], a3 = ar[48 + glane];

            float d = dot4h(a0, v0) + dot4h(a1, v1) + dot4h(a2, v2) + dot4h(a3, v3);
            float q = dot4(v0, v0) + dot4(v1, v1) + dot4(v2, v2) + dot4(v3, v3);
            #pragma unroll
            for (int off = 8; off > 0; off >>= 1) {
                d += __shfl_xor(d, off);
                q += __shfl_xor(q, off);
            }
            if (glane == 0 && valid)
                ssim[wid][it + group] = d * rsqrtf(fmaxf(q, 1e-30f));
        }
    }
    if (lane < NEG_PER_WAVE && base + lane < N) {
        const float t = fmaxf(MARGIN + ssim[wid][lane] - ps[b_all], 0.0f);
        const unsigned long long pk =
            (unsigned long long)(t * FIXSCALE + 0.5f) + (1ULL << 40);
        atomicAdd(&acc[b_all], pk);
    }
}

extern "C" void kernel_launch(void* const* d_in, const int* in_sizes, int n_in,
                              void* d_out, int out_size, void* d_ws, size_t ws_size,
                              hipStream_t stream) {
    const float* anchor = (const float*)d_in[0];
    const float* pos    = (const float*)d_in[1];
    const float* neg    = (const float*)d_in[2];
    const int*   idx    = (const int*)d_in[3];

    const int D = 256;
    int B = in_sizes[0] / D;   // 4096
    int N = in_sizes[3];       // 262144

    const int threads = 256;
    const int negs_per_block = (threads / 64) * NEG_PER_WAVE;           // 128
    const int nblocks = (N + negs_per_block - 1) / negs_per_block;      // 2048

    // tier-1 workspace layout
    size_t o = 0;
    _Float16*           a_h    = (_Float16*)d_ws;            o += (size_t)B * 256 * sizeof(_Float16);
    float*              ps     = (float*)((char*)d_ws + o);  o += (size_t)B * sizeof(float);
    unsigned long long* acc    = (unsigned long long*)((char*)d_ws + o); o += (size_t)B * sizeof(unsigned long long);
    unsigned*           cnt    = (unsigned*)((char*)d_ws + o); o += (size_t)B * sizeof(unsigned);
    unsigned*           offb   = (unsigned*)((char*)d_ws + o); o += (size_t)B * sizeof(unsigned);
    unsigned long long* sorted = (unsigned long long*)((char*)d_ws + o); o += (size_t)N * sizeof(unsigned long long);
    const size_t need_sorted = o;
    const size_t need_plain  = (size_t)B * 256 * sizeof(_Float16)
                             + (size_t)B * sizeof(float)
                             + (size_t)B * sizeof(unsigned long long);

    if (ws_size >= need_sorted && B <= 4096) {
        // -------- tier 1: sorted gather --------
        hipMemsetAsync(cnt, 0, (size_t)B * sizeof(unsigned), stream);
        pos_hist_kernel<<<(B + 3) / 4, threads, 0, stream>>>(
            anchor, pos, idx, a_h, ps, acc, cnt, B, N);
        scan_kernel<<<1, 1024, 0, stream>>>(cnt, offb, B);
        scatter_kernel<<<(N + threads - 1) / threads, threads, 0, stream>>>(
            idx, offb, sorted, N);
        neg_h_sorted<<<nblocks, threads, 0, stream>>>(a_h, neg, sorted, ps,
                                                      acc, N);
        finalize_packed_kernel<<<1, 1024, 0, stream>>>(acc, (float*)d_out, B);
    } else if (ws_size >= need_plain) {
        // -------- tier 2: unsorted fp16 (R10 path) --------
        pos_h_kernel<<<(B + 3) / 4, threads, 0, stream>>>(anchor, pos, a_h, ps,
                                                          acc, B);
        neg_h_kernel<<<nblocks, threads, 0, stream>>>(a_h, neg, idx, ps,
                                                      acc, N);
        finalize_packed_kernel<<<1, 1024, 0, stream>>>(acc, (float*)d_out, B);
    }
}

// Round 13
// 69.132 us; speedup vs baseline: 1.4527x; 1.4527x over previous
//
#include <hip/hip_runtime.h>
#include <math.h>

#define EPS 1e-8f
#define MARGIN 0.5f
#define NEG_PER_WAVE 32
#define FIXSCALE 1048576.0f            // 2^20 fixed-point for t
#define MASK40 ((1ULL << 40) - 1)
#define NBUCKET 8

typedef float    f4 __attribute__((ext_vector_type(4)));
typedef _Float16 h4 __attribute__((ext_vector_type(4)));

__device__ __forceinline__ float dot4(const f4 a, const f4 b) {
    return a.x * b.x + a.y * b.y + a.z * b.z + a.w * b.w;
}
__device__ __forceinline__ float dot4h(const h4 a, const f4 b) {
    return (float)a.x * b.x + (float)a.y * b.y + (float)a.z * b.z + (float)a.w * b.w;
}
__device__ __forceinline__ int bucket_of(int b, int B) {
    return (int)(((long long)b * NBUCKET) / B);
}

// ================= Tier 1: bucketed fp16-anchor path ========================

// Kernel A: pos cosine + normalized fp16 anchors + zero accums + per-block
// bucket histogram (LDS). Grid = NB blocks x 256 (NB = (B+3)/4).
__global__ void pos_h_count_kernel(const float* __restrict__ anchor,
                                   const float* __restrict__ pos,
                                   const int*  __restrict__ idx,
                                   _Float16* __restrict__ a_h,
                                   float* __restrict__ ps,
                                   unsigned long long* __restrict__ acc,
                                   unsigned* __restrict__ blkcnt,
                                   int B, int N, int chunk) {
    __shared__ unsigned hcnt[NBUCKET];
    const int tid  = blockIdx.x * blockDim.x + threadIdx.x;
    const int row  = tid >> 6;
    const int lane = threadIdx.x & 63;

    if (threadIdx.x < NBUCKET) hcnt[threadIdx.x] = 0u;
    __syncthreads();

    if (tid < 2 * B) ((unsigned int*)acc)[tid] = 0u;

    // histogram of this block's idx chunk
    {
        const long long lo = (long long)blockIdx.x * chunk;
        const long long hi = (lo + chunk < N) ? lo + chunk : N;
        for (long long i = lo + threadIdx.x; i < hi; i += blockDim.x)
            atomicAdd(&hcnt[bucket_of(idx[i], B)], 1u);
    }

    if (row < B) {
        const f4 a = *(reinterpret_cast<const f4*>(anchor + (size_t)row * 256) + lane);
        const f4 p = *(reinterpret_cast<const f4*>(pos    + (size_t)row * 256) + lane);

        float dot = dot4(a, p), na = dot4(a, a), nb = dot4(p, p);
        #pragma unroll
        for (int off = 32; off > 0; off >>= 1) {
            dot += __shfl_xor(dot, off);
            na  += __shfl_xor(na,  off);
            nb  += __shfl_xor(nb,  off);
        }
        const float sna   = sqrtf(na);
        const float scale = 1.0f / fmaxf(sna, 1e-20f);
        h4 ah;
        ah.x = (_Float16)(a.x * scale); ah.y = (_Float16)(a.y * scale);
        ah.z = (_Float16)(a.z * scale); ah.w = (_Float16)(a.w * scale);
        *(reinterpret_cast<h4*>(a_h + (size_t)row * 256) + lane) = ah;
        if (lane == 0) ps[row] = dot / fmaxf(sna * sqrtf(nb), EPS);
    }

    __syncthreads();
    if (threadIdx.x < NBUCKET)
        blkcnt[threadIdx.x * gridDim.x + blockIdx.x] = hcnt[threadIdx.x];
}

// Kernel B: exclusive scan of blkcnt (bucket-major, M = 8*NB <= 8192) -> off.
__global__ void __launch_bounds__(1024) scan_kernel(
        const unsigned* __restrict__ blkcnt,
        unsigned* __restrict__ off, int M) {
    __shared__ unsigned tsum[1024];
    const int t = threadIdx.x;
    unsigned c[8];
    unsigned s = 0;
    #pragma unroll
    for (int j = 0; j < 8; ++j) {
        const int i = t * 8 + j;
        c[j] = (i < M) ? blkcnt[i] : 0u;
        s += c[j];
    }
    tsum[t] = s;
    __syncthreads();
    for (int o = 1; o < 1024; o <<= 1) {
        const unsigned v = (t >= o) ? tsum[t - o] : 0u;
        __syncthreads();
        tsum[t] += v;
        __syncthreads();
    }
    unsigned pre = (t > 0) ? tsum[t - 1] : 0u;
    #pragma unroll
    for (int j = 0; j < 8; ++j) {
        const int i = t * 8 + j;
        if (i < M) off[i] = pre;
        pre += c[j];
    }
}

// Kernel C: scatter packed (b<<18 | n) into bucket order, block-local so
// within-bucket order stays ~increasing n (keeps neg reads near-sequential).
__global__ void scatter_kernel(const int* __restrict__ idx,
                               const unsigned* __restrict__ off,
                               unsigned* __restrict__ pk,
                               int B, int N, int chunk) {
    __shared__ unsigned loff[NBUCKET];
    if (threadIdx.x < NBUCKET)
        loff[threadIdx.x] = off[threadIdx.x * gridDim.x + blockIdx.x];
    __syncthreads();
    const long long lo = (long long)blockIdx.x * chunk;
    const long long hi = (lo + chunk < N) ? lo + chunk : N;
    for (long long i = lo + threadIdx.x; i < hi; i += blockDim.x) {
        const int b = idx[i];
        const int g = bucket_of(b, B);
        const unsigned p = atomicAdd(&loff[g], 1u);
        pk[p] = ((unsigned)b << 18) | (unsigned)i;
    }
}

// Kernel D: bucketed negatives. Group g = blockIdx%8 (XCD heuristic) owns
// bucket g -> 256KB a_h slice stays L2-resident (touch interval << turnover).
__global__ void __launch_bounds__(256) neg_h_bucketed(
        const _Float16* __restrict__ a_h,
        const float* __restrict__ neg,
        const unsigned* __restrict__ pk,
        const unsigned* __restrict__ off,
        const float* __restrict__ ps,
        unsigned long long* __restrict__ acc,
        int N, int NB) {
    __shared__ float ssim[4][NEG_PER_WAVE];

    const int lane  = threadIdx.x & 63;
    const int wid   = threadIdx.x >> 6;
    const int group = lane >> 4;
    const int glane = lane & 15;

    const int g  = blockIdx.x & 7;
    const int jg = blockIdx.x >> 3;
    const unsigned base = off[g * NB];
    const unsigned end  = (g < 7) ? off[(g + 1) * NB] : (unsigned)N;
    const unsigned wvidx   = (unsigned)(jg * 4 + wid);
    const unsigned wstride = (gridDim.x >> 3) * 4u * NEG_PER_WAVE;

    for (unsigned s = base + wvidx * NEG_PER_WAVE; s < end; s += wstride) {
        int b_all = 0, n_all = 0;
        if (lane < NEG_PER_WAVE && s + lane < end) {
            const unsigned e = pk[s + lane];
            b_all = (int)(e >> 18);
            n_all = (int)(e & 0x3FFFFu);
        }

        #pragma unroll 2
        for (int it = 0; it < NEG_PER_WAVE; it += 4) {
            const bool valid = (s + it + group) < end;
            const int b = __shfl(b_all, it + group);
            const int n = __shfl(n_all, it + group);
            const int bb = valid ? b : 0;
            const int nn = valid ? n : 0;

            const f4* nr = reinterpret_cast<const f4*>(neg + (size_t)nn * 256);
            const h4* ar = reinterpret_cast<const h4*>(a_h + (size_t)bb * 256);

            const f4 v0 = nr[ 0 + glane], v1 = nr[16 + glane],
                     v2 = nr[32 + glane], v3 = nr[48 + glane];
            const h4 a0 = ar[ 0 + glane], a1 = ar[16 + glane],
                     a2 = ar[32 + glane], a3 = ar[48 + glane];

            float d = dot4h(a0, v0) + dot4h(a1, v1) + dot4h(a2, v2) + dot4h(a3, v3);
            float q = dot4(v0, v0) + dot4(v1, v1) + dot4(v2, v2) + dot4(v3, v3);

            #pragma unroll
            for (int o = 8; o > 0; o >>= 1) {
                d += __shfl_xor(d, o);
                q += __shfl_xor(q, o);
            }
            if (glane == 0 && valid)
                ssim[wid][it + group] = d * rsqrtf(fmaxf(q, 1e-30f));
        }

        if (lane < NEG_PER_WAVE && s + lane < end) {
            const float t = fmaxf(MARGIN + ssim[wid][lane] - ps[b_all], 0.0f);
            const unsigned long long pk64 =
                (unsigned long long)(t * FIXSCALE + 0.5f) + (1ULL << 40);
            atomicAdd(&acc[b_all], pk64);
        }
    }
}

// Kernel E: unpack u64 accums -> segment means -> scalar (one block).
__global__ void __launch_bounds__(1024) finalize_packed_kernel(
        const unsigned long long* __restrict__ acc,
        float* __restrict__ out, int B) {
    float local = 0.0f;
    for (int i = threadIdx.x; i < B; i += blockDim.x) {
        const unsigned long long v = acc[i];
        const float c = (float)(v >> 40);
        const float s = (float)(v & MASK40) * (1.0f / FIXSCALE);
        local += (c > 0.0f) ? (s / c) : 0.0f;
    }
    #pragma unroll
    for (int off = 32; off > 0; off >>= 1)
        local += __shfl_xor(local, off);

    __shared__ float ws[16];
    const int wid = threadIdx.x >> 6;
    if ((threadIdx.x & 63) == 0) ws[wid] = local;
    __syncthreads();
    if (threadIdx.x == 0) {
        float tot = 0.0f;
        const int nw = blockDim.x >> 6;
        for (int w = 0; w < nw; ++w) tot += ws[w];
        out[0] = tot / (float)B;
    }
}

// ============ Tier 2: unsorted fp16 path (R10/R11, proven 61.7 µs) ==========

__global__ void pos_h_kernel(const float* __restrict__ anchor,
                             const float* __restrict__ pos,
                             _Float16* __restrict__ a_h,
                             float* __restrict__ ps,
                             unsigned long long* __restrict__ acc,
                             int B) {
    const int tid  = blockIdx.x * blockDim.x + threadIdx.x;
    const int row  = tid >> 6;
    const int lane = threadIdx.x & 63;

    if (tid < 2 * B) ((unsigned int*)acc)[tid] = 0u;
    if (row >= B) return;

    const f4 a = *(reinterpret_cast<const f4*>(anchor + (size_t)row * 256) + lane);
    const f4 p = *(reinterpret_cast<const f4*>(pos    + (size_t)row * 256) + lane);

    float dot = dot4(a, p), na = dot4(a, a), nb = dot4(p, p);
    #pragma unroll
    for (int off = 32; off > 0; off >>= 1) {
        dot += __shfl_xor(dot, off);
        na  += __shfl_xor(na,  off);
        nb  += __shfl_xor(nb,  off);
    }
    const float sna   = sqrtf(na);
    const float scale = 1.0f / fmaxf(sna, 1e-20f);
    h4 ah;
    ah.x = (_Float16)(a.x * scale); ah.y = (_Float16)(a.y * scale);
    ah.z = (_Float16)(a.z * scale); ah.w = (_Float16)(a.w * scale);
    *(reinterpret_cast<h4*>(a_h + (size_t)row * 256) + lane) = ah;
    if (lane == 0) ps[row] = dot / fmaxf(sna * sqrtf(nb), EPS);
}

__global__ void __launch_bounds__(256) neg_h_kernel(
        const _Float16* __restrict__ a_h,
        const float* __restrict__ neg,
        const int*  __restrict__ idx,
        const float* __restrict__ ps,
        unsigned long long* __restrict__ acc,
        int N) {
    __shared__ float ssim[4][NEG_PER_WAVE];
    const int lane  = threadIdx.x & 63;
    const int wid   = threadIdx.x >> 6;
    const int group = lane >> 4;
    const int glane = lane & 15;
    const long long base =
        ((long long)blockIdx.x * (blockDim.x >> 6) + wid) * NEG_PER_WAVE;

    int b_all = 0;
    {
        const long long in = base + lane;
        if (lane < NEG_PER_WAVE && in < N) b_all = idx[in];
    }
    if (base < N) {
        #pragma unroll 2
        for (int it = 0; it < NEG_PER_WAVE; it += 4) {
            const long long n = base + it + group;
            const bool valid = (n < N);
            const long long ns = valid ? n : (long long)0;
            const int b = __shfl(b_all, it + group);

            const f4* nr = reinterpret_cast<const f4*>(neg + (size_t)ns * 256);
            const h4* ar = reinterpret_cast<const h4*>(a_h + (size_t)b * 256);
            const f4 v0 = nr[ 0 + glane], v1 = nr[16 + glane],
                     v2 = nr[32 + glane], v3 = nr[48 + glane];
            const h4 a0 = ar[ 0 + glane], a1 = ar[16 + glane],
                     a2 = ar[32 + glane], a3 = ar[48 + glane];

            float d = dot4h(a0, v0) + dot4h(a1, v1) + dot4h(a2, v2) + dot4h(a3, v3);
            float q = dot4(v0, v0) + dot4(v1, v1) + dot4(v2, v2) + dot4(v3, v3);
            #pragma unroll
            for (int off = 8; off > 0; off >>= 1) {
                d += __shfl_xor(d, off);
                q += __shfl_xor(q, off);
            }
            if (glane == 0 && valid)
                ssim[wid][it + group] = d * rsqrtf(fmaxf(q, 1e-30f));
        }
    }
    if (lane < NEG_PER_WAVE && base + lane < N) {
        const float t = fmaxf(MARGIN + ssim[wid][lane] - ps[b_all], 0.0f);
        const unsigned long long pk =
            (unsigned long long)(t * FIXSCALE + 0.5f) + (1ULL << 40);
        atomicAdd(&acc[b_all], pk);
    }
}

extern "C" void kernel_launch(void* const* d_in, const int* in_sizes, int n_in,
                              void* d_out, int out_size, void* d_ws, size_t ws_size,
                              hipStream_t stream) {
    const float* anchor = (const float*)d_in[0];
    const float* pos    = (const float*)d_in[1];
    const float* neg    = (const float*)d_in[2];
    const int*   idx    = (const int*)d_in[3];

    const int D = 256;
    int B = in_sizes[0] / D;   // 4096
    int N = in_sizes[3];       // 262144

    const int threads = 256;
    const int negs_per_block = (threads / 64) * NEG_PER_WAVE;           // 128
    const int nblocks = (N + negs_per_block - 1) / negs_per_block;      // 2048

    const int NB    = (B + 3) / 4;                    // 1024 for B=4096
    const int M     = NBUCKET * NB;                   // 8192
    const int chunk = (N + NB - 1) / NB;              // 256

    // tier-1 workspace layout
    size_t o = 0;
    _Float16*           a_h    = (_Float16*)d_ws;                        o += (size_t)B * 256 * sizeof(_Float16);
    float*              ps     = (float*)((char*)d_ws + o);              o += (size_t)B * sizeof(float);
    unsigned long long* acc    = (unsigned long long*)((char*)d_ws + o); o += (size_t)B * sizeof(unsigned long long);
    unsigned*           blkcnt = (unsigned*)((char*)d_ws + o);           o += (size_t)M * sizeof(unsigned);
    unsigned*           offb   = (unsigned*)((char*)d_ws + o);           o += (size_t)M * sizeof(unsigned);
    unsigned*           pk     = (unsigned*)((char*)d_ws + o);           o += (size_t)N * sizeof(unsigned);
    const size_t need1 = o;
    const size_t need2 = (size_t)B * 256 * sizeof(_Float16)
                       + (size_t)B * sizeof(float)
                       + (size_t)B * sizeof(unsigned long long);

    const bool tier1_ok = (B <= 4096) && (N <= (1 << 18)) && (ws_size >= need1);

    if (tier1_ok) {
        // -------- tier 1: bucketed gather --------
        pos_h_count_kernel<<<NB, threads, 0, stream>>>(
            anchor, pos, idx, a_h, ps, acc, blkcnt, B, N, chunk);
        scan_kernel<<<1, 1024, 0, stream>>>(blkcnt, offb, M);
        scatter_kernel<<<NB, threads, 0, stream>>>(idx, offb, pk, B, N, chunk);
        neg_h_bucketed<<<nblocks, threads, 0, stream>>>(
            a_h, neg, pk, offb, ps, acc, N, NB);
        finalize_packed_kernel<<<1, 1024, 0, stream>>>(acc, (float*)d_out, B);
    } else if (ws_size >= need2) {
        // -------- tier 2: unsorted fp16 (proven R10/R11 path) --------
        pos_h_kernel<<<(B + 3) / 4, threads, 0, stream>>>(anchor, pos, a_h, ps,
                                                          acc, B);
        neg_h_kernel<<<nblocks, threads, 0, stream>>>(a_h, neg, idx, ps,
                                                      acc, N);
        finalize_packed_kernel<<<1, 1024, 0, stream>>>(acc, (float*)d_out, B);
    }
}

// Round 14
// 62.275 us; speedup vs baseline: 1.6126x; 1.1101x over previous
//
#include <hip/hip_runtime.h>
#include <math.h>

#define EPS 1e-8f
#define MARGIN 0.5f
#define NEG_PER_WAVE 32
#define FIXSCALE 1048576.0f            // 2^20 fixed-point for t
#define MASK40 ((1ULL << 40) - 1)

typedef float    f4 __attribute__((ext_vector_type(4)));
typedef _Float16 h4 __attribute__((ext_vector_type(4)));

__device__ __forceinline__ float dot4(const f4 a, const f4 b) {
    return a.x * b.x + a.y * b.y + a.z * b.z + a.w * b.w;
}
__device__ __forceinline__ float dot4h(const h4 a, const f4 b) {
    return (float)a.x * b.x + (float)a.y * b.y + (float)a.z * b.z + (float)a.w * b.w;
}

// ============================ FP16-anchor path ==============================

// Kernel 1h: pos cosine + normalized fp16 anchor table + zero u64 accums.
__global__ void pos_h_kernel(const float* __restrict__ anchor,
                             const float* __restrict__ pos,
                             _Float16* __restrict__ a_h,
                             float* __restrict__ ps,
                             unsigned long long* __restrict__ acc,
                             int B) {
    const int tid  = blockIdx.x * blockDim.x + threadIdx.x;
    const int row  = tid >> 6;
    const int lane = threadIdx.x & 63;

    if (tid < 2 * B) ((unsigned int*)acc)[tid] = 0u;
    if (row >= B) return;

    const f4 a = *(reinterpret_cast<const f4*>(anchor + (size_t)row * 256) + lane);
    const f4 p = *(reinterpret_cast<const f4*>(pos    + (size_t)row * 256) + lane);

    float dot = dot4(a, p), na = dot4(a, a), nb = dot4(p, p);
    #pragma unroll
    for (int off = 32; off > 0; off >>= 1) {
        dot += __shfl_xor(dot, off);
        na  += __shfl_xor(na,  off);
        nb  += __shfl_xor(nb,  off);
    }
    const float sna   = sqrtf(na);
    const float scale = 1.0f / fmaxf(sna, 1e-20f);
    h4 ah;
    ah.x = (_Float16)(a.x * scale); ah.y = (_Float16)(a.y * scale);
    ah.z = (_Float16)(a.z * scale); ah.w = (_Float16)(a.w * scale);
    *(reinterpret_cast<h4*>(a_h + (size_t)row * 256) + lane) = ah;
    if (lane == 0) ps[row] = dot / fmaxf(sna * sqrtf(nb), EPS);
}

// Kernel 2h: CONTIGUOUS loads — all 64 lanes on one row per instruction
// (1 KB neg / 512 B a_h per load, the coalescing sweet spot). 4 rows per
// iteration; quadrant-rotation butterfly reduces 4 (d,q) pairs in 14
// shuffles. idx hoisted; one packed u64 atomic per negative at wave end.
__global__ void __launch_bounds__(256) neg_h_kernel(
        const _Float16* __restrict__ a_h,
        const float* __restrict__ neg,
        const int*  __restrict__ idx,
        const float* __restrict__ ps,
        unsigned long long* __restrict__ acc,
        int N) {
    __shared__ float ssim[4][NEG_PER_WAVE];

    const int lane = threadIdx.x & 63;
    const int wid  = threadIdx.x >> 6;
    const long long base =
        ((long long)blockIdx.x * (blockDim.x >> 6) + wid) * NEG_PER_WAVE;

    // hoisted index load: lanes 0..31 fetch this wave's 32 indices (128 B)
    int b_all = 0;
    {
        const long long in = base + lane;
        if (lane < NEG_PER_WAVE && in < N) b_all = idx[in];
    }

    const bool hi32 = (lane & 32) != 0;
    const bool hi16 = (lane & 16) != 0;

    if (base + NEG_PER_WAVE <= N) {
        // ---- fast path: full tile ----
        #pragma unroll 2
        for (int it = 0; it < NEG_PER_WAVE; it += 4) {
            const int b0 = __shfl(b_all, it + 0);
            const int b1 = __shfl(b_all, it + 1);
            const int b2 = __shfl(b_all, it + 2);
            const int b3 = __shfl(b_all, it + 3);

            const long long n0 = base + it;
            // neg rows: 64 lanes x 16 B = contiguous 1 KB per instruction
            const f4 v0 = reinterpret_cast<const f4*>(neg + (size_t)(n0 + 0) * 256)[lane];
            const f4 v1 = reinterpret_cast<const f4*>(neg + (size_t)(n0 + 1) * 256)[lane];
            const f4 v2 = reinterpret_cast<const f4*>(neg + (size_t)(n0 + 2) * 256)[lane];
            const f4 v3 = reinterpret_cast<const f4*>(neg + (size_t)(n0 + 3) * 256)[lane];
            // a_h rows: 64 lanes x 8 B = contiguous 512 B per instruction
            const h4 a0 = reinterpret_cast<const h4*>(a_h + (size_t)b0 * 256)[lane];
            const h4 a1 = reinterpret_cast<const h4*>(a_h + (size_t)b1 * 256)[lane];
            const h4 a2 = reinterpret_cast<const h4*>(a_h + (size_t)b2 * 256)[lane];
            const h4 a3 = reinterpret_cast<const h4*>(a_h + (size_t)b3 * 256)[lane];

            float d0 = dot4h(a0, v0), q0 = dot4(v0, v0);
            float d1 = dot4h(a1, v1), q1 = dot4(v1, v1);
            float d2 = dot4h(a2, v2), q2 = dot4(v2, v2);
            float d3 = dot4h(a3, v3), q3 = dot4(v3, v3);

            // --- quadrant-rotation reduce: 14 shuffles for 4 (d,q) pairs ---
            // step xor-32: quadrant half keeps rows {2*bit5, 2*bit5+1}
            float dA = (hi32 ? d2 : d0) + __shfl_xor(hi32 ? d0 : d2, 32);
            float dB = (hi32 ? d3 : d1) + __shfl_xor(hi32 ? d1 : d3, 32);
            float qA = (hi32 ? q2 : q0) + __shfl_xor(hi32 ? q0 : q2, 32);
            float qB = (hi32 ? q3 : q1) + __shfl_xor(hi32 ? q1 : q3, 32);
            // step xor-16: quadrant keeps row 2*bit5 + bit4
            float dC = (hi16 ? dB : dA) + __shfl_xor(hi16 ? dA : dB, 16);
            float qC = (hi16 ? qB : qA) + __shfl_xor(hi16 ? qA : qB, 16);
            // within-16 butterfly
            #pragma unroll
            for (int off = 8; off > 0; off >>= 1) {
                dC += __shfl_xor(dC, off);
                qC += __shfl_xor(qC, off);
            }
            // quadrant qd's glane==0 holds row it+qd
            if ((lane & 15) == 0)
                ssim[wid][it + (lane >> 4)] = dC * rsqrtf(fmaxf(qC, 1e-30f));
        }
    } else if (base < N) {
        // ---- slow path: partial tile (guarded per row) ----
        for (int it = 0; it < NEG_PER_WAVE; it += 4) {
            float dr[4], qr[4];
            #pragma unroll
            for (int j = 0; j < 4; ++j) {
                const long long n = base + it + j;
                const bool valid = (n < N);
                const long long ns = valid ? n : (long long)0;
                const int b = __shfl(b_all, it + j);
                const f4 v = reinterpret_cast<const f4*>(neg + (size_t)ns * 256)[lane];
                const h4 a = reinterpret_cast<const h4*>(a_h + (size_t)b * 256)[lane];
                dr[j] = valid ? dot4h(a, v) : 0.0f;
                qr[j] = valid ? dot4(v, v)  : 1.0f;
            }
            float dA = (hi32 ? dr[2] : dr[0]) + __shfl_xor(hi32 ? dr[0] : dr[2], 32);
            float dB = (hi32 ? dr[3] : dr[1]) + __shfl_xor(hi32 ? dr[1] : dr[3], 32);
            float qA = (hi32 ? qr[2] : qr[0]) + __shfl_xor(hi32 ? qr[0] : qr[2], 32);
            float qB = (hi32 ? qr[3] : qr[1]) + __shfl_xor(hi32 ? qr[1] : qr[3], 32);
            float dC = (hi16 ? dB : dA) + __shfl_xor(hi16 ? dA : dB, 16);
            float qC = (hi16 ? qB : qA) + __shfl_xor(hi16 ? qA : qB, 16);
            #pragma unroll
            for (int off = 8; off > 0; off >>= 1) {
                dC += __shfl_xor(dC, off);
                qC += __shfl_xor(qC, off);
            }
            if ((lane & 15) == 0)
                ssim[wid][it + (lane >> 4)] = dC * rsqrtf(fmaxf(qC, 1e-30f));
        }
    }

    // wave-local flush: lane L owns negative base+L; b is lane's own b_all.
    if (lane < NEG_PER_WAVE && base + lane < N) {
        const float t = fmaxf(MARGIN + ssim[wid][lane] - ps[b_all], 0.0f);
        const unsigned long long pk =
            (unsigned long long)(t * FIXSCALE + 0.5f) + (1ULL << 40);
        atomicAdd(&acc[b_all], pk);
    }
}

// Kernel 3h: unpack u64 accums -> segment means -> scalar (one block).
__global__ void __launch_bounds__(1024) finalize_packed_kernel(
        const unsigned long long* __restrict__ acc,
        float* __restrict__ out, int B) {
    float local = 0.0f;
    for (int i = threadIdx.x; i < B; i += blockDim.x) {
        const unsigned long long v = acc[i];
        const float c = (float)(v >> 40);
        const float s = (float)(v & MASK40) * (1.0f / FIXSCALE);
        local += (c > 0.0f) ? (s / c) : 0.0f;
    }
    #pragma unroll
    for (int off = 32; off > 0; off >>= 1)
        local += __shfl_xor(local, off);

    __shared__ float ws[16];
    const int wid = threadIdx.x >> 6;
    if ((threadIdx.x & 63) == 0) ws[wid] = local;
    __syncthreads();
    if (threadIdx.x == 0) {
        float tot = 0.0f;
        const int nw = blockDim.x >> 6;
        for (int w = 0; w < nw; ++w) tot += ws[w];
        out[0] = tot / (float)B;
    }
}

// ===================== Fallback (fp32, known-good) ==========================

__global__ void pos_sim_kernel(const float* __restrict__ anchor,
                               const float* __restrict__ pos,
                               float2* __restrict__ pn,
                               float* __restrict__ sums,
                               float* __restrict__ counts,
                               int B) {
    const int tid  = blockIdx.x * blockDim.x + threadIdx.x;
    const int wave = tid >> 6;
    const int lane = threadIdx.x & 63;
    if (tid < B) sums[tid] = 0.0f;
    else if (tid < 2 * B) counts[tid - B] = 0.0f;
    if (wave >= B) return;
    const f4 a = *(reinterpret_cast<const f4*>(anchor + (size_t)wave * 256) + lane);
    const f4 p = *(reinterpret_cast<const f4*>(pos    + (size_t)wave * 256) + lane);
    float dot = dot4(a, p), na = dot4(a, a), nb = dot4(p, p);
    #pragma unroll
    for (int off = 32; off > 0; off >>= 1) {
        dot += __shfl_xor(dot, off);
        na  += __shfl_xor(na,  off);
        nb  += __shfl_xor(nb,  off);
    }
    if (lane == 0) {
        float sna = sqrtf(na);
        float2 r; r.x = dot / fmaxf(sna * sqrtf(nb), EPS); r.y = sna;
        pn[wave] = r;
    }
}

__global__ void __launch_bounds__(256) neg_kernel(
        const float* __restrict__ anchor,
        const float* __restrict__ neg,
        const int*  __restrict__ idx,
        const float2* __restrict__ pn,
        float* __restrict__ sums,
        float* __restrict__ counts,
        int N) {
    const int lane  = threadIdx.x & 63;
    const int wid   = threadIdx.x >> 6;
    const int group = lane >> 4;
    const int glane = lane & 15;
    const long long base =
        ((long long)blockIdx.x * (blockDim.x >> 6) + wid) * NEG_PER_WAVE;
    if (base >= N) return;
    for (int it = 0; it < NEG_PER_WAVE; it += 4) {
        const long long n = base + it + group;
        if (n >= N) continue;
        const int b = idx[n];
        const f4* ar = reinterpret_cast<const f4*>(anchor + (size_t)b * 256);
        const f4* nr = reinterpret_cast<const f4*>(neg + (size_t)n * 256);
        float d = 0.0f, q = 0.0f;
        #pragma unroll
        for (int c = 0; c < 4; ++c) {
            const f4 a = ar[c * 16 + glane];
            const f4 v = nr[c * 16 + glane];
            d += dot4(a, v); q += dot4(v, v);
        }
        #pragma unroll
        for (int off = 8; off > 0; off >>= 1) {
            d += __shfl_xor(d, off);
            q += __shfl_xor(q, off);
        }
        if (glane == 0) {
            const float2 p = pn[b];
            float t = fmaxf(MARGIN + d / fmaxf(p.y * sqrtf(q), EPS) - p.x, 0.0f);
            atomicAdd(&sums[b], t);
            atomicAdd(&counts[b], 1.0f);
        }
    }
}

__global__ void __launch_bounds__(1024) finalize_kernel(
        const float* __restrict__ sums,
        const float* __restrict__ counts,
        float* __restrict__ out, int B) {
    float local = 0.0f;
    for (int i = threadIdx.x; i < B; i += blockDim.x) {
        float c = counts[i];
        local += (c > 0.0f) ? (sums[i] / c) : 0.0f;
    }
    #pragma unroll
    for (int off = 32; off > 0; off >>= 1)
        local += __shfl_xor(local, off);

    __shared__ float ws[16];
    const int wid = threadIdx.x >> 6;
    if ((threadIdx.x & 63) == 0) ws[wid] = local;
    __syncthreads();
    if (threadIdx.x == 0) {
        float tot = 0.0f;
        const int nw = blockDim.x >> 6;
        for (int w = 0; w < nw; ++w) tot += ws[w];
        out[0] = tot / (float)B;
    }
}

extern "C" void kernel_launch(void* const* d_in, const int* in_sizes, int n_in,
                              void* d_out, int out_size, void* d_ws, size_t ws_size,
                              hipStream_t stream) {
    const float* anchor = (const float*)d_in[0];
    const float* pos    = (const float*)d_in[1];
    const float* neg    = (const float*)d_in[2];
    const int*   idx    = (const int*)d_in[3];

    const int D = 256;
    int B = in_sizes[0] / D;   // 4096
    int N = in_sizes[3];       // 262144

    const size_t need_h = (size_t)B * 256 * sizeof(_Float16)            // a_h
                        + (size_t)B * sizeof(float)                     // ps
                        + (size_t)B * sizeof(unsigned long long);       // acc

    const int threads = 256;
    const int negs_per_block = (threads / 64) * NEG_PER_WAVE;           // 128
    const int nblocks = (N + negs_per_block - 1) / negs_per_block;      // 2048

    if (ws_size >= need_h) {
        _Float16*           a_h = (_Float16*)d_ws;
        float*              ps  = (float*)(a_h + (size_t)B * 256);
        unsigned long long* acc = (unsigned long long*)(ps + B);

        pos_h_kernel<<<(B + 3) / 4, threads, 0, stream>>>(anchor, pos, a_h, ps,
                                                          acc, B);
        neg_h_kernel<<<nblocks, threads, 0, stream>>>(a_h, neg, idx, ps,
                                                      acc, N);
        finalize_packed_kernel<<<1, 1024, 0, stream>>>(acc, (float*)d_out, B);
    } else {
        // fallback: known-good fp32 path
        float2* pn     = (float2*)d_ws;
        float*  sums   = (float*)(pn + B);
        float*  counts = sums + B;

        pos_sim_kernel<<<(B + 3) / 4, threads, 0, stream>>>(anchor, pos, pn,
                                                            sums, counts, B);
        neg_kernel<<<nblocks, threads, 0, stream>>>(anchor, neg, idx, pn,
                                                    sums, counts, N);
        finalize_kernel<<<1, 1024, 0, stream>>>(sums, counts, (float*)d_out, B);
    }
}